// Round 7
// baseline (184.181 us; speedup 1.0000x reference)
//
#include <hip/hip_runtime.h>
#include <cstdint>

#define NB 4
#define ND 1024
#define NT 2048
#define NH 16
#define NE 64
#define GLEN 2240  // per-copy length of reversed global Toeplitz table (elements)
#define CAP 2312   // per-copy length of LDS table (elements)

typedef __bf16 bf16x8 __attribute__((ext_vector_type(8)));
typedef float f32x4 __attribute__((ext_vector_type(4)));
typedef unsigned short us8 __attribute__((ext_vector_type(8)));
typedef unsigned short us4 __attribute__((ext_vector_type(4)));

__device__ __forceinline__ unsigned short f2bf(float f) {
  unsigned u = __builtin_bit_cast(unsigned, f);
  return (unsigned short)((u + 0x7fffu + ((u >> 16) & 1u)) >> 16);  // RTNE
}

// async global->LDS, 16B per lane; LDS dest must be wave-uniform base + lane*16
__device__ __forceinline__ void gload16(const void* g, void* l) {
  __builtin_amdgcn_global_load_lds(
      (const __attribute__((address_space(1))) void*)(uintptr_t)g,
      (__attribute__((address_space(3))) void*)(uintptr_t)l, 16, 0, 0);
}

// ---------------------------------------------------------------- prep ------
__global__ void prep_kernel(const float* __restrict__ Wp, const float* __restrict__ Wo,
                            const float* __restrict__ tw,
                            unsigned short* __restrict__ WpB, unsigned short* __restrict__ WoB,
                            unsigned short* __restrict__ Gr8) {
  int idx = blockIdx.x * 256 + threadIdx.x;
  int stride = gridDim.x * 256;
  const int n4 = ND * ND / 4;
  for (int i = idx; i < n4; i += stride) {
    float4 v = ((const float4*)Wp)[i];
    us4 o = {f2bf(v.x), f2bf(v.y), f2bf(v.z), f2bf(v.w)};
    ((us4*)WpB)[i] = o;
  }
  for (int i = idx; i < n4; i += stride) {
    float4 v = ((const float4*)Wo)[i];
    us4 o = {f2bf(v.x), f2bf(v.y), f2bf(v.z), f2bf(v.w)};
    ((us4*)WoB)[i] = o;
  }
  for (int i = idx; i < NH * 8 * GLEN; i += stride) {
    int h = i / (8 * GLEN);
    int rem = i - h * 8 * GLEN;
    int r = rem / GLEN;
    int c = rem - r * GLEN;
    int src = c + r;
    Gr8[i] = (src <= NT - 1) ? f2bf(tw[h * NT + (NT - 1) - src]) : (unsigned short)0;
  }
}

// ------------------------------------------------------- transpose + cast ---
__global__ __launch_bounds__(256) void transpose_cast(const float* __restrict__ x,
                                                      unsigned short* __restrict__ xT) {
  __shared__ float tile[64][65];
  const int c = threadIdx.x & 15, r = threadIdx.x >> 4;
  const int t0 = blockIdx.x * 64, d0 = blockIdx.y * 64, b = blockIdx.z;
  const float* xb = x + (long)b * ND * NT;
#pragma unroll
  for (int k = 0; k < 4; ++k) {
    float4 v = *(const float4*)&xb[(long)(d0 + r + 16 * k) * NT + t0 + 4 * c];
    tile[r + 16 * k][4 * c + 0] = v.x;
    tile[r + 16 * k][4 * c + 1] = v.y;
    tile[r + 16 * k][4 * c + 2] = v.z;
    tile[r + 16 * k][4 * c + 3] = v.w;
  }
  __syncthreads();
  unsigned short* xTb = xT + (long)b * NT * ND;
#pragma unroll
  for (int k = 0; k < 4; ++k) {
    int t = r + 16 * k;
    us4 o = {f2bf(tile[4 * c + 0][t]), f2bf(tile[4 * c + 1][t]), f2bf(tile[4 * c + 2][t]),
             f2bf(tile[4 * c + 3][t])};
    *(us4*)&xTb[(long)(t0 + t) * ND + d0 + 4 * c] = o;
  }
}

// ----------------------------------------------------------- gemm_bt --------
// Batch-fused: C[m][n] = sum_k A[m][k] * BT[n][k] + bias[m], M=1024, N=8192
// (n = b*2048 + t; BT = flat (B*T, D) matrix), K=1024.
// 128x256 block tile, 4 waves of 64x128 (av[4] x bv[8] -> acc[4][8]):
// 12 ds_read_b128 per 32 MFMA -> MFMA is the critical pipe (was 8 per 16).
// Double-buffered LDS (48 KB), one stage per 32-K window. Grid 256 = 1/CU.
// Epilogue maps n -> (b, t): addr = ((b*ND + m)*NT + t).
template <bool OUT_BF16>
__global__ __launch_bounds__(256, 1) void gemm_bt(const unsigned short* __restrict__ A,
                                                  const unsigned short* __restrict__ BT,
                                                  const float* __restrict__ bias,
                                                  void* __restrict__ Cb) {
  const int K = 1024;
  __shared__ __align__(16) unsigned short As[2][128 * 32];  // 16 KB
  __shared__ __align__(16) unsigned short Bs[2][256 * 32];  // 32 KB
  const int tid = threadIdx.x, lane = tid & 63, wid = tid >> 6;
  const int wm = (wid & 1) * 64, wn = (wid >> 1) * 128;
  const int m0 = blockIdx.y * 128, n0 = blockIdx.x * 256;
  const int mlo = lane & 15, q = lane >> 4;

  f32x4 acc[4][8] = {};
  auto stage = [&](int buf, int k0) {
#pragma unroll
    for (int p = 0; p < 2; ++p) {
      int idx = p * 256 + tid;
      int row = idx >> 2, kc = (idx & 3) * 8;
      gload16(A + (long)(m0 + row) * K + k0 + kc, &As[buf][idx * 8]);
    }
#pragma unroll
    for (int p = 0; p < 4; ++p) {
      int idx = p * 256 + tid;
      int row = idx >> 2, kc = (idx & 3) * 8;
      gload16(BT + (long)(n0 + row) * K + k0 + kc, &Bs[buf][idx * 8]);
    }
  };
  auto compute = [&](int buf) {
    bf16x8 av[4], bv[8];
#pragma unroll
    for (int i = 0; i < 4; ++i)
      av[i] = __builtin_bit_cast(bf16x8, *(const us8*)&As[buf][(wm + i * 16 + mlo) * 32 + q * 8]);
#pragma unroll
    for (int j = 0; j < 8; ++j)
      bv[j] = __builtin_bit_cast(bf16x8, *(const us8*)&Bs[buf][(wn + j * 16 + mlo) * 32 + q * 8]);
#pragma unroll
    for (int i = 0; i < 4; ++i)
#pragma unroll
      for (int j = 0; j < 8; ++j)
        acc[i][j] = __builtin_amdgcn_mfma_f32_16x16x32_bf16(av[i], bv[j], acc[i][j], 0, 0, 0);
  };

  stage(0, 0);
#pragma unroll 1
  for (int k0 = 0; k0 < K; k0 += 64) {
    __syncthreads();
    stage(1, k0 + 32);
    compute(0);
    __syncthreads();
    if (k0 + 64 < K) stage(0, k0 + 64);
    compute(1);
  }
  // epilogue: C/D layout col=lane&15, row=(lane>>4)*4+r; n -> (b,t)
  const int bb = n0 >> 11;
  const int tbase = (n0 & 2047) + wn;
#pragma unroll
  for (int i = 0; i < 4; ++i)
#pragma unroll
    for (int j = 0; j < 8; ++j)
#pragma unroll
      for (int r = 0; r < 4; ++r) {
        int gr = m0 + wm + i * 16 + q * 4 + r;
        int t = tbase + j * 16 + mlo;
        float v = acc[i][j][r] + bias[gr];
        long addr = ((long)bb * ND + gr) * NT + t;
        if (OUT_BF16)
          ((unsigned short*)Cb)[addr] = f2bf(v);
        else
          ((float*)Cb)[addr] = v;
      }
}

// ----------------------------------------------------------- toeplitz -------
// Unchanged from R6 (BK=64, A-rotation, deterministic pair balance).
__global__ __launch_bounds__(256, 2) void toeplitz(const unsigned short* __restrict__ proj,
                                                   const unsigned short* __restrict__ Gr8,
                                                   unsigned short* __restrict__ mixedT) {
  __shared__ __align__(16) unsigned short Ls[8 * CAP];        // 36992 B
  __shared__ __align__(16) unsigned short Bs[2][2][64 * 32];  // 16384 B
  const int tid = threadIdx.x, lane = tid & 63, w = tid >> 6;
  const int j = blockIdx.x, h = blockIdx.y, bz = blockIdx.z;
  const int mlo = lane & 15, q = lane >> 4;
  const int wt = (w >> 1) * 64, we = (w & 1) * 32;
  const int t0L = (15 - j) * 128, t0S = j * 128;

  const int delta = (NT - 128) - t0L;
  const int MUSE = t0L + 256;
#pragma unroll 1
  for (int r = 0; r < 8; ++r) {
    int rr = (r + delta) & 7;
    int off8 = r + delta - rr;
    const unsigned short* src = Gr8 + (long)(h * 8 + rr) * GLEN + off8;
    unsigned short* dst = &Ls[r * CAP];
    for (int mc = tid; mc * 8 < MUSE; mc += 256) gload16(src + mc * 8, dst + mc * 8);
  }

  const int rA = (7 - mlo) & 7;
  const int eRow = tid >> 2, kCol = (tid & 3) * 8;
  const unsigned short* bsrc = proj + ((long)bz * ND + h * 64 + eRow) * NT + kCol;

#pragma unroll 1
  for (int p = 0; p < 2; ++p) {
    const int t0p = p ? t0S : t0L;
    const int kend = t0p + 128;
    const unsigned short* lA = &Ls[rA * CAP + (127 - wt - mlo - rA) + q * 8 + (t0L - t0p)];
    gload16(bsrc, &Bs[0][0][tid * 8]);
    gload16(bsrc + 32, &Bs[0][1][tid * 8]);
    __syncthreads();
    bf16x8 ap0 = __builtin_bit_cast(bf16x8, *(const us8*)(lA - 32));
    bf16x8 ap1 = __builtin_bit_cast(bf16x8, *(const us8*)(lA - 48));
    f32x4 acc[4][2] = {};

    auto sub = [&](int bf, int hh, int s) {
      bf16x8 a0 = __builtin_bit_cast(bf16x8, *(const us8*)(lA + s));
      bf16x8 a1 = __builtin_bit_cast(bf16x8, *(const us8*)(lA + s - 16));
      bf16x8 b0 = __builtin_bit_cast(bf16x8, *(const us8*)&Bs[bf][hh][(we + mlo) * 32 + q * 8]);
      bf16x8 b1 =
          __builtin_bit_cast(bf16x8, *(const us8*)&Bs[bf][hh][(we + 16 + mlo) * 32 + q * 8]);
      acc[0][0] = __builtin_amdgcn_mfma_f32_16x16x32_bf16(a0, b0, acc[0][0], 0, 0, 0);
      acc[0][1] = __builtin_amdgcn_mfma_f32_16x16x32_bf16(a0, b1, acc[0][1], 0, 0, 0);
      acc[1][0] = __builtin_amdgcn_mfma_f32_16x16x32_bf16(a1, b0, acc[1][0], 0, 0, 0);
      acc[1][1] = __builtin_amdgcn_mfma_f32_16x16x32_bf16(a1, b1, acc[1][1], 0, 0, 0);
      acc[2][0] = __builtin_amdgcn_mfma_f32_16x16x32_bf16(ap0, b0, acc[2][0], 0, 0, 0);
      acc[2][1] = __builtin_amdgcn_mfma_f32_16x16x32_bf16(ap0, b1, acc[2][1], 0, 0, 0);
      acc[3][0] = __builtin_amdgcn_mfma_f32_16x16x32_bf16(ap1, b0, acc[3][0], 0, 0, 0);
      acc[3][1] = __builtin_amdgcn_mfma_f32_16x16x32_bf16(ap1, b1, acc[3][1], 0, 0, 0);
      ap0 = a0;
      ap1 = a1;
    };

#pragma unroll 1
    for (int s0 = 0; s0 < kend; s0 += 128) {
      gload16(bsrc + s0 + 64, &Bs[1][0][tid * 8]);
      gload16(bsrc + s0 + 96, &Bs[1][1][tid * 8]);
      sub(0, 0, s0);
      sub(0, 1, s0 + 32);
      __syncthreads();
      if (s0 + 128 < kend) {
        gload16(bsrc + s0 + 128, &Bs[0][0][tid * 8]);
        gload16(bsrc + s0 + 160, &Bs[0][1][tid * 8]);
      }
      sub(1, 0, s0 + 64);
      sub(1, 1, s0 + 96);
      __syncthreads();
    }
#pragma unroll
    for (int i = 0; i < 4; ++i)
#pragma unroll
      for (int jj = 0; jj < 2; ++jj)
#pragma unroll
        for (int rr = 0; rr < 4; ++rr) {
          int t = t0p + wt + i * 16 + q * 4 + rr;
          int e = we + jj * 16 + mlo;
          mixedT[((long)bz * NT + t) * ND + h * 64 + e] = f2bf(acc[i][jj][rr]);
        }
  }
}

// ---------------------------------------------------------------------------
extern "C" void kernel_launch(void* const* d_in, const int* in_sizes, int n_in, void* d_out,
                              int out_size, void* d_ws, size_t ws_size, hipStream_t stream) {
  const float* x = (const float*)d_in[0];
  const float* Wp = (const float*)d_in[1];
  const float* bp = (const float*)d_in[2];
  const float* tw = (const float*)d_in[3];
  const float* Wo = (const float*)d_in[4];
  const float* bo = (const float*)d_in[5];
  float* out = (float*)d_out;

  char* ws = (char*)d_ws;
  unsigned short* xT = (unsigned short*)(ws);  // flat (B*T, D); also mixedT after stage 2
  unsigned short* proj = (unsigned short*)(ws + (16ull << 20));
  unsigned short* WpB = (unsigned short*)(ws + (32ull << 20));
  unsigned short* WoB = (unsigned short*)(ws + (34ull << 20));
  unsigned short* Gr8 = (unsigned short*)(ws + (36ull << 20));

  prep_kernel<<<dim3(1024), 256, 0, stream>>>(Wp, Wo, tw, WpB, WoB, Gr8);
  transpose_cast<<<dim3(NT / 64, ND / 64, NB), 256, 0, stream>>>(x, xT);
  // stage 1: proj[b][he][t] = Wp @ xT[b*T+t]^T + bp   (N = B*T fused)
  gemm_bt<true><<<dim3(32, 8), 256, 0, stream>>>(WpB, xT, bp, proj);
  // stage 2: mixedT[b][t][he] (written into xT buffer)
  toeplitz<<<dim3(8, NH, NB), 256, 0, stream>>>(proj, Gr8, xT);
  // stage 3: out[b][d][t] = Wo @ mixedT[b*T+t]^T + bo
  gemm_bt<false><<<dim3(32, 8), 256, 0, stream>>>(WoB, xT, bo, out);
}

// Round 8
// 173.891 us; speedup vs baseline: 1.0592x; 1.0592x over previous
//
#include <hip/hip_runtime.h>
#include <cstdint>

#define NB 4
#define ND 1024
#define NT 2048
#define NH 16
#define NE 64
#define GLEN 2240  // per-copy length of reversed global Toeplitz table (elements)
#define CAP 2312   // per-copy length of LDS table (elements)

typedef __bf16 bf16x8 __attribute__((ext_vector_type(8)));
typedef float f32x4 __attribute__((ext_vector_type(4)));
typedef float f32x16 __attribute__((ext_vector_type(16)));
typedef unsigned short us8 __attribute__((ext_vector_type(8)));
typedef unsigned short us4 __attribute__((ext_vector_type(4)));

__device__ __forceinline__ unsigned short f2bf(float f) {
  unsigned u = __builtin_bit_cast(unsigned, f);
  return (unsigned short)((u + 0x7fffu + ((u >> 16) & 1u)) >> 16);  // RTNE
}

// async global->LDS, 16B per lane; LDS dest must be wave-uniform base + lane*16
__device__ __forceinline__ void gload16(const void* g, void* l) {
  __builtin_amdgcn_global_load_lds(
      (const __attribute__((address_space(1))) void*)(uintptr_t)g,
      (__attribute__((address_space(3))) void*)(uintptr_t)l, 16, 0, 0);
}

// ---------------------------------------------------------------- prep ------
__global__ void prep_kernel(const float* __restrict__ Wp, const float* __restrict__ Wo,
                            const float* __restrict__ tw,
                            unsigned short* __restrict__ WpB, unsigned short* __restrict__ WoB,
                            unsigned short* __restrict__ Gr8) {
  int idx = blockIdx.x * 256 + threadIdx.x;
  int stride = gridDim.x * 256;
  const int n4 = ND * ND / 4;
  for (int i = idx; i < n4; i += stride) {
    float4 v = ((const float4*)Wp)[i];
    us4 o = {f2bf(v.x), f2bf(v.y), f2bf(v.z), f2bf(v.w)};
    ((us4*)WpB)[i] = o;
  }
  for (int i = idx; i < n4; i += stride) {
    float4 v = ((const float4*)Wo)[i];
    us4 o = {f2bf(v.x), f2bf(v.y), f2bf(v.z), f2bf(v.w)};
    ((us4*)WoB)[i] = o;
  }
  for (int i = idx; i < NH * 8 * GLEN; i += stride) {
    int h = i / (8 * GLEN);
    int rem = i - h * 8 * GLEN;
    int r = rem / GLEN;
    int c = rem - r * GLEN;
    int src = c + r;
    Gr8[i] = (src <= NT - 1) ? f2bf(tw[h * NT + (NT - 1) - src]) : (unsigned short)0;
  }
}

// ------------------------------------------------------- transpose + cast ---
__global__ __launch_bounds__(256) void transpose_cast(const float* __restrict__ x,
                                                      unsigned short* __restrict__ xT) {
  __shared__ float tile[64][65];
  const int c = threadIdx.x & 15, r = threadIdx.x >> 4;
  const int t0 = blockIdx.x * 64, d0 = blockIdx.y * 64, b = blockIdx.z;
  const float* xb = x + (long)b * ND * NT;
#pragma unroll
  for (int k = 0; k < 4; ++k) {
    float4 v = *(const float4*)&xb[(long)(d0 + r + 16 * k) * NT + t0 + 4 * c];
    tile[r + 16 * k][4 * c + 0] = v.x;
    tile[r + 16 * k][4 * c + 1] = v.y;
    tile[r + 16 * k][4 * c + 2] = v.z;
    tile[r + 16 * k][4 * c + 3] = v.w;
  }
  __syncthreads();
  unsigned short* xTb = xT + (long)b * NT * ND;
#pragma unroll
  for (int k = 0; k < 4; ++k) {
    int t = r + 16 * k;
    us4 o = {f2bf(tile[4 * c + 0][t]), f2bf(tile[4 * c + 1][t]), f2bf(tile[4 * c + 2][t]),
             f2bf(tile[4 * c + 3][t])};
    *(us4*)&xTb[(long)(t0 + t) * ND + d0 + 4 * c] = o;
  }
}

// ----------------------------------------------------------- gemm_bt --------
// C[b][m][n] = sum_k A[m][k] * Bt[b][n][k] + bias[m]
// 128x128 tile, BK=64 (two 32-col half-arrays), double-buffered, 2 blocks/CU.
// MFMA shape 32x32x16 (m119: 2495 TF ceiling, half the issue count of
// 16x16x32): wave tile 64x64 = 2x2 MFMAs; A[m=lane&31][k=(lane>>5)*8+j],
// C/D col=lane&31, row=(reg&3)+8*(reg>>2)+4*(lane>>5) (m74/m101-verified).
template <bool OUT_BF16>
__global__ __launch_bounds__(256, 2) void gemm_bt(const unsigned short* __restrict__ A,
                                                  const unsigned short* __restrict__ Bt,
                                                  const float* __restrict__ bias,
                                                  void* __restrict__ Cb, long strideB,
                                                  long strideC) {
  const int N = 2048, K = 1024;
  __shared__ __align__(16) unsigned short As[2][2][128 * 32];  // [buf][k-half]
  __shared__ __align__(16) unsigned short Bs[2][2][128 * 32];
  const int tid = threadIdx.x;
  const int lane = tid & 63;
  const int wid = tid >> 6;
  const int wm = (wid & 1) * 64, wn = (wid >> 1) * 64;
  const int m0 = blockIdx.y * 128, n0 = blockIdx.x * 128;
  const unsigned short* Bb = Bt + (long)blockIdx.z * strideB;
  const int nlo = lane & 31, half = lane >> 5;

  f32x16 acc[2][2] = {};
  auto stage = [&](int buf, int k0) {
#pragma unroll
    for (int hh = 0; hh < 2; ++hh)
#pragma unroll
      for (int p = 0; p < 2; ++p) {
        int idx = p * 256 + tid;
        int row = idx >> 2, kc = (idx & 3) * 8;
        gload16(A + (long)(m0 + row) * K + k0 + hh * 32 + kc, &As[buf][hh][idx * 8]);
        gload16(Bb + (long)(n0 + row) * K + k0 + hh * 32 + kc, &Bs[buf][hh][idx * 8]);
      }
  };
  auto compute = [&](int buf) {
#pragma unroll
    for (int hh = 0; hh < 2; ++hh)
#pragma unroll
      for (int s = 0; s < 2; ++s) {
        const int col = half * 8 + s * 16;
        bf16x8 av[2], bv[2];
#pragma unroll
        for (int i = 0; i < 2; ++i) {
          av[i] =
              __builtin_bit_cast(bf16x8, *(const us8*)&As[buf][hh][(wm + i * 32 + nlo) * 32 + col]);
          bv[i] =
              __builtin_bit_cast(bf16x8, *(const us8*)&Bs[buf][hh][(wn + i * 32 + nlo) * 32 + col]);
        }
#pragma unroll
        for (int i = 0; i < 2; ++i)
#pragma unroll
          for (int j = 0; j < 2; ++j)
            acc[i][j] = __builtin_amdgcn_mfma_f32_32x32x16_bf16(av[i], bv[j], acc[i][j], 0, 0, 0);
      }
  };

  stage(0, 0);
#pragma unroll 1
  for (int k0 = 0; k0 < K; k0 += 128) {
    __syncthreads();
    stage(1, k0 + 64);  // K multiple of 128 -> always in range
    compute(0);
    __syncthreads();
    if (k0 + 128 < K) stage(0, k0 + 128);
    compute(1);
  }
  // epilogue: C/D col=lane&31, row=(reg&3)+8*(reg>>2)+4*(lane>>5)
#pragma unroll
  for (int i = 0; i < 2; ++i)
#pragma unroll
    for (int j = 0; j < 2; ++j)
#pragma unroll
      for (int reg = 0; reg < 16; ++reg) {
        int gr = m0 + wm + i * 32 + (reg & 3) + 8 * (reg >> 2) + 4 * half;
        int gc = n0 + wn + j * 32 + nlo;
        float v = acc[i][j][reg] + bias[gr];
        if (OUT_BF16)
          ((unsigned short*)Cb)[(long)blockIdx.z * strideC + (long)gr * N + gc] = f2bf(v);
        else
          ((float*)Cb)[(long)blockIdx.z * strideC + (long)gr * N + gc] = v;
      }
}

// ----------------------------------------------------------- toeplitz -------
// Unchanged from R6 (BK=64, A-rotation, deterministic pair balance).
__global__ __launch_bounds__(256, 2) void toeplitz(const unsigned short* __restrict__ proj,
                                                   const unsigned short* __restrict__ Gr8,
                                                   unsigned short* __restrict__ mixedT) {
  __shared__ __align__(16) unsigned short Ls[8 * CAP];        // 36992 B
  __shared__ __align__(16) unsigned short Bs[2][2][64 * 32];  // 16384 B
  const int tid = threadIdx.x, lane = tid & 63, w = tid >> 6;
  const int j = blockIdx.x, h = blockIdx.y, bz = blockIdx.z;
  const int mlo = lane & 15, q = lane >> 4;
  const int wt = (w >> 1) * 64, we = (w & 1) * 32;
  const int t0L = (15 - j) * 128, t0S = j * 128;

  const int delta = (NT - 128) - t0L;
  const int MUSE = t0L + 256;
#pragma unroll 1
  for (int r = 0; r < 8; ++r) {
    int rr = (r + delta) & 7;
    int off8 = r + delta - rr;
    const unsigned short* src = Gr8 + (long)(h * 8 + rr) * GLEN + off8;
    unsigned short* dst = &Ls[r * CAP];
    for (int mc = tid; mc * 8 < MUSE; mc += 256) gload16(src + mc * 8, dst + mc * 8);
  }

  const int rA = (7 - mlo) & 7;
  const int eRow = tid >> 2, kCol = (tid & 3) * 8;
  const unsigned short* bsrc = proj + ((long)bz * ND + h * 64 + eRow) * NT + kCol;

#pragma unroll 1
  for (int p = 0; p < 2; ++p) {
    const int t0p = p ? t0S : t0L;
    const int kend = t0p + 128;
    const unsigned short* lA = &Ls[rA * CAP + (127 - wt - mlo - rA) + q * 8 + (t0L - t0p)];
    gload16(bsrc, &Bs[0][0][tid * 8]);
    gload16(bsrc + 32, &Bs[0][1][tid * 8]);
    __syncthreads();
    bf16x8 ap0 = __builtin_bit_cast(bf16x8, *(const us8*)(lA - 32));
    bf16x8 ap1 = __builtin_bit_cast(bf16x8, *(const us8*)(lA - 48));
    f32x4 acc[4][2] = {};

    auto sub = [&](int bf, int hh, int s) {
      bf16x8 a0 = __builtin_bit_cast(bf16x8, *(const us8*)(lA + s));
      bf16x8 a1 = __builtin_bit_cast(bf16x8, *(const us8*)(lA + s - 16));
      bf16x8 b0 = __builtin_bit_cast(bf16x8, *(const us8*)&Bs[bf][hh][(we + mlo) * 32 + q * 8]);
      bf16x8 b1 =
          __builtin_bit_cast(bf16x8, *(const us8*)&Bs[bf][hh][(we + 16 + mlo) * 32 + q * 8]);
      acc[0][0] = __builtin_amdgcn_mfma_f32_16x16x32_bf16(a0, b0, acc[0][0], 0, 0, 0);
      acc[0][1] = __builtin_amdgcn_mfma_f32_16x16x32_bf16(a0, b1, acc[0][1], 0, 0, 0);
      acc[1][0] = __builtin_amdgcn_mfma_f32_16x16x32_bf16(a1, b0, acc[1][0], 0, 0, 0);
      acc[1][1] = __builtin_amdgcn_mfma_f32_16x16x32_bf16(a1, b1, acc[1][1], 0, 0, 0);
      acc[2][0] = __builtin_amdgcn_mfma_f32_16x16x32_bf16(ap0, b0, acc[2][0], 0, 0, 0);
      acc[2][1] = __builtin_amdgcn_mfma_f32_16x16x32_bf16(ap0, b1, acc[2][1], 0, 0, 0);
      acc[3][0] = __builtin_amdgcn_mfma_f32_16x16x32_bf16(ap1, b0, acc[3][0], 0, 0, 0);
      acc[3][1] = __builtin_amdgcn_mfma_f32_16x16x32_bf16(ap1, b1, acc[3][1], 0, 0, 0);
      ap0 = a0;
      ap1 = a1;
    };

#pragma unroll 1
    for (int s0 = 0; s0 < kend; s0 += 128) {
      gload16(bsrc + s0 + 64, &Bs[1][0][tid * 8]);
      gload16(bsrc + s0 + 96, &Bs[1][1][tid * 8]);
      sub(0, 0, s0);
      sub(0, 1, s0 + 32);
      __syncthreads();
      if (s0 + 128 < kend) {
        gload16(bsrc + s0 + 128, &Bs[0][0][tid * 8]);
        gload16(bsrc + s0 + 160, &Bs[0][1][tid * 8]);
      }
      sub(1, 0, s0 + 64);
      sub(1, 1, s0 + 96);
      __syncthreads();
    }
#pragma unroll
    for (int i = 0; i < 4; ++i)
#pragma unroll
      for (int jj = 0; jj < 2; ++jj)
#pragma unroll
        for (int rr = 0; rr < 4; ++rr) {
          int t = t0p + wt + i * 16 + q * 4 + rr;
          int e = we + jj * 16 + mlo;
          mixedT[((long)bz * NT + t) * ND + h * 64 + e] = f2bf(acc[i][jj][rr]);
        }
  }
}

// ---------------------------------------------------------------------------
extern "C" void kernel_launch(void* const* d_in, const int* in_sizes, int n_in, void* d_out,
                              int out_size, void* d_ws, size_t ws_size, hipStream_t stream) {
  const float* x = (const float*)d_in[0];
  const float* Wp = (const float*)d_in[1];
  const float* bp = (const float*)d_in[2];
  const float* tw = (const float*)d_in[3];
  const float* Wo = (const float*)d_in[4];
  const float* bo = (const float*)d_in[5];
  float* out = (float*)d_out;

  char* ws = (char*)d_ws;
  unsigned short* xT = (unsigned short*)(ws);  // also mixedT after stage 2
  unsigned short* proj = (unsigned short*)(ws + (16ull << 20));
  unsigned short* WpB = (unsigned short*)(ws + (32ull << 20));
  unsigned short* WoB = (unsigned short*)(ws + (34ull << 20));
  unsigned short* Gr8 = (unsigned short*)(ws + (36ull << 20));

  prep_kernel<<<dim3(1024), 256, 0, stream>>>(Wp, Wo, tw, WpB, WoB, Gr8);
  transpose_cast<<<dim3(NT / 64, ND / 64, NB), 256, 0, stream>>>(x, xT);
  gemm_bt<true><<<dim3(16, 8, NB), 256, 0, stream>>>(WpB, xT, bp, proj, (long)NT * ND,
                                                     (long)ND * NT);
  toeplitz<<<dim3(8, NH, NB), 256, 0, stream>>>(proj, Gr8, xT);
  gemm_bt<false><<<dim3(16, 8, NB), 256, 0, stream>>>(WoB, xT, bo, out, (long)NT * ND,
                                                      (long)ND * NT);
}